// Round 6
// baseline (282.142 us; speedup 1.0000x reference)
//
#include <hip/hip_runtime.h>

typedef __bf16 bf16;
typedef __bf16 bf16x8 __attribute__((ext_vector_type(8)));
typedef _Float16 f16;
typedef _Float16 f16x8 __attribute__((ext_vector_type(8)));
typedef float f32x4 __attribute__((ext_vector_type(4)));
typedef short s16x8 __attribute__((ext_vector_type(8)));

#define SCALE 0.125f
#define AP 72   // bf16 LDS row stride for attn/ckv tiles (64 + 8 pad)
#define CT 128  // bf16 LDS row stride for 128-wide C-tile (aliases As|Bs exactly, 32KB)

// ---------------------------------------------------------------------------
// async global->LDS, 16B per lane (wave-uniform LDS base + lane*16 layout)
// ---------------------------------------------------------------------------
__device__ __forceinline__ void async_ld16(const void* g, void* l) {
  __builtin_amdgcn_global_load_lds((const __attribute__((address_space(1))) void*)g,
                                   (__attribute__((address_space(3))) void*)l, 16, 0, 0);
}

// ---------------------------------------------------------------------------
// Pass 0: convert/split inputs (float4-vectorized).
// ---------------------------------------------------------------------------
__global__ __launch_bounds__(256) void k_convert(
    const float* __restrict__ x, const float* __restrict__ wqkv, const float* __restrict__ wo,
    bf16* __restrict__ xsplit, bf16* __restrict__ wsplit, f16* __restrict__ wo16)
{
  const int N1 = 2097152, N2 = 786432, N3 = 262144;  // in float4 units
  const int i = blockIdx.x * 256 + threadIdx.x;
  if (i < N1) {
    f32x4 v = ((const f32x4*)x)[i];
    int e = i * 4, m = e >> 10, c = e & 1023;
    bf16 hi[4], lo[4];
#pragma unroll
    for (int u = 0; u < 4; ++u) { hi[u] = (bf16)v[u]; lo[u] = (bf16)(v[u] - (float)hi[u]); }
    *(ulong1*)&xsplit[(size_t)m * 2048 + c] = *(ulong1*)hi;
    *(ulong1*)&xsplit[(size_t)m * 2048 + 1024 + c] = *(ulong1*)lo;
  } else if (i < N1 + N2) {
    int j = i - N1;
    f32x4 v = ((const f32x4*)wqkv)[j];
    int e = j * 4, n = e >> 10, c = e & 1023;
    bf16 hi[4], lo[4];
#pragma unroll
    for (int u = 0; u < 4; ++u) { hi[u] = (bf16)v[u]; lo[u] = (bf16)(v[u] - (float)hi[u]); }
    *(ulong1*)&wsplit[(size_t)n * 2048 + c] = *(ulong1*)hi;
    *(ulong1*)&wsplit[(size_t)n * 2048 + 1024 + c] = *(ulong1*)lo;
  } else if (i < N1 + N2 + N3) {
    int j = i - N1 - N2;
    f32x4 v = ((const f32x4*)wo)[j];
    f16 h[4];
#pragma unroll
    for (int u = 0; u < 4; ++u) h[u] = (f16)v[u];
    *(ulong1*)&wo16[(size_t)j * 4] = *(ulong1*)h;
  }
}

// ---------------------------------------------------------------------------
// Pass 1: QKV GEMM (R3-proven: fused 3-term K/V path, conflict-free swizzle,
// full-drain __syncthreads, XCD-aware remap mb = l&63 -> 134us, FETCH 79MB).
// ---------------------------------------------------------------------------
__global__ __launch_bounds__(256) void k_gemm_qkv(
    const bf16* __restrict__ A, const bf16* __restrict__ B,
    bf16* __restrict__ Qws, bf16* __restrict__ Kws, bf16* __restrict__ Vws)
{
  __shared__ char smem[32768];
  const int tid = threadIdx.x;
  const int wave = tid >> 6, lane = tid & 63;
  const int quad = lane >> 4, l16 = lane & 15;
  // XCD-aware remap: l -> (mb, nbr); mb = l&63 pins each A-panel to one XCD.
  const int l = blockIdx.x;
  int mb, nbr;
  if (l < 1024) { mb = l & 63; nbr = 8 + (l >> 6); }       // K,V blocks first
  else          { const int q = l - 1024; mb = q & 63; nbr = q >> 6; }  // Q
  const int n0 = nbr * 128;
  const int m0 = mb * 128;
  const int wm = (wave >> 1) << 6, wn = (wave & 1) << 6;
  const int region = n0 >> 10;  // 0=q, 1=k, 2=v
  f32x4 acc[4][4] = {};

  if (region == 0) {
    bf16* As = (bf16*)smem;
    bf16* Bs = As + 128 * 64;
    const int r8 = lane >> 3, c8 = lane & 7;
    const int sw = l16 & 7;
    const int srcoff = (c8 ^ r8) * 8;
    for (int k0 = 0; k0 < 1024; k0 += 64) {
      __syncthreads();
#pragma unroll
      for (int it = 0; it < 4; ++it) {
        const int row = wave * 32 + it * 8 + r8;
        async_ld16(A + (size_t)(m0 + row) * 2048 + k0 + srcoff, As + row * 64 + c8 * 8);
        async_ld16(B + (size_t)(n0 + row) * 2048 + k0 + srcoff, Bs + row * 64 + c8 * 8);
      }
      __syncthreads();
#pragma unroll
      for (int ks = 0; ks < 64; ks += 32) {
        bf16x8 af[4], bg[4];
#pragma unroll
        for (int mi = 0; mi < 4; ++mi)
          af[mi] = *(const bf16x8*)&As[(wm + mi * 16 + l16) * 64 + ((((ks >> 3) + quad) ^ sw) << 3)];
#pragma unroll
        for (int ni = 0; ni < 4; ++ni)
          bg[ni] = *(const bf16x8*)&Bs[(wn + ni * 16 + l16) * 64 + ((((ks >> 3) + quad) ^ sw) << 3)];
#pragma unroll
        for (int mi = 0; mi < 4; ++mi)
#pragma unroll
          for (int ni = 0; ni < 4; ++ni)
            acc[mi][ni] = __builtin_amdgcn_mfma_f32_16x16x32_bf16(af[mi], bg[ni], acc[mi][ni], 0, 0, 0);
      }
    }
  } else {
    bf16* Ah = (bf16*)smem;
    bf16* Al = Ah + 128 * 32;
    bf16* Bh = Al + 128 * 32;
    bf16* Bl = Bh + 128 * 32;
    const int rr0 = tid >> 2;
    const int sl = tid & 3;
    const int rsw = quad ^ ((l16 >> 1) & 3);
    for (int k0 = 0; k0 < 1024; k0 += 32) {
      __syncthreads();
#pragma unroll
      for (int rr = 0; rr < 2; ++rr) {
        const int row = rr * 64 + rr0;
        const int soff = ((sl ^ ((row >> 1) & 3)) << 3);
        const bf16* arow = A + (size_t)(m0 + row) * 2048 + k0 + soff;
        const bf16* brow = B + (size_t)(n0 + row) * 2048 + k0 + soff;
        async_ld16(arow,        Ah + row * 32 + sl * 8);
        async_ld16(arow + 1024, Al + row * 32 + sl * 8);
        async_ld16(brow,        Bh + row * 32 + sl * 8);
        async_ld16(brow + 1024, Bl + row * 32 + sl * 8);
      }
      __syncthreads();
#pragma unroll
      for (int cb = 0; cb < 3; ++cb) {
        const bf16* Asrc = (cb == 1) ? Al : Ah;
        const bf16* Bsrc = (cb == 2) ? Bl : Bh;
        bf16x8 af[4], bg[4];
#pragma unroll
        for (int mi = 0; mi < 4; ++mi)
          af[mi] = *(const bf16x8*)&Asrc[(wm + mi * 16 + l16) * 32 + (rsw << 3)];
#pragma unroll
        for (int ni = 0; ni < 4; ++ni)
          bg[ni] = *(const bf16x8*)&Bsrc[(wn + ni * 16 + l16) * 32 + (rsw << 3)];
#pragma unroll
        for (int mi = 0; mi < 4; ++mi)
#pragma unroll
          for (int ni = 0; ni < 4; ++ni)
            acc[mi][ni] = __builtin_amdgcn_mfma_f32_16x16x32_bf16(af[mi], bg[ni], acc[mi][ni], 0, 0, 0);
      }
    }
  }

  bf16* Ct = (bf16*)smem;
  __syncthreads();
#pragma unroll
  for (int mi = 0; mi < 4; ++mi) {
    const int ml = wm + mi * 16 + quad * 4;
#pragma unroll
    for (int ni = 0; ni < 4; ++ni) {
      const int nl = wn + ni * 16 + l16;
#pragma unroll
      for (int r = 0; r < 4; ++r) {
        const float v = acc[mi][ni][r];
        bf16 o;
        if (region == 0) o = (bf16)(v * SCALE);
        else             o = (bf16)((v >= 0.f) ? 1.f : -1.f);
        Ct[(ml + r) * CT + nl] = o;
      }
    }
  }
  __syncthreads();
  {
    const int row = tid >> 1, half = tid & 1;
    const int nn = (n0 & 1023) + half * 64;
    const int h = nn >> 6;
    const int b = m0 >> 12, t = (m0 & 4095) + row;
    bf16* base = (region == 0) ? Qws : (region == 1) ? Kws : Vws;
    bf16* dst = base + ((size_t)(b * 16 + h) * 4096 + t) * 64;
    const bf16* src = &Ct[row * CT + half * 64];
#pragma unroll
    for (int u = 0; u < 8; ++u)
      *(bf16x8*)(dst + u * 8) = *(const bf16x8*)(src + u * 8);
  }
}

// ---------------------------------------------------------------------------
// Pass 2: per-chunk KV outer product via MFMA -> int16, TRANSPOSED output:
// ckv_t[dd(v)][i(k)] = sum_t V[t][dd] K[t][i] (A-operand = V rows, B = K rows).
// Exact ints |v|<=64. Transpose is free (operand swap) and lets k_scan emit
// Ph/Pl in the [v][k] layout k_attn's B-fragments consume directly.
// ---------------------------------------------------------------------------
__global__ __launch_bounds__(256) void k_ckv(
    const bf16* __restrict__ Kws, const bf16* __restrict__ Vws, short* __restrict__ ckv)
{
  __shared__ bf16 Kt[64 * AP];  // [i][t]
  __shared__ bf16 Vt[64 * AP];  // [dd][t]
  const int tid = threadIdx.x;
  const int nchunk = blockIdx.x & 63, bh = blockIdx.x >> 6;
  const size_t tbase = ((size_t)bh * 4096 + (size_t)nchunk * 64) * 64;
  const int row = tid >> 2, c0 = (tid & 3) << 4;
  {
    const bf16x8* gk = (const bf16x8*)(Kws + tbase + row * 64 + c0);
    const bf16x8* gv = (const bf16x8*)(Vws + tbase + row * 64 + c0);
    bf16x8 k0 = gk[0], k1 = gk[1], v0 = gv[0], v1 = gv[1];
#pragma unroll
    for (int u = 0; u < 8; ++u) {
      Kt[(c0 + u) * AP + row] = k0[u];
      Kt[(c0 + 8 + u) * AP + row] = k1[u];
      Vt[(c0 + u) * AP + row] = v0[u];
      Vt[(c0 + 8 + u) * AP + row] = v1[u];
    }
  }
  __syncthreads();
  const int wave = tid >> 6, lane = tid & 63;
  const int quad = lane >> 4, l16 = lane & 15;
  const int ti = wave;
  bf16x8 va[2];   // A-operand: V rows (dd)
#pragma unroll
  for (int kk = 0; kk < 2; ++kk)
    va[kk] = *(const bf16x8*)&Vt[(ti * 16 + l16) * AP + kk * 32 + quad * 8];
  short* dst = ckv + ((size_t)bh * 64 + nchunk) * 4096;
#pragma unroll
  for (int td = 0; td < 4; ++td) {
    f32x4 acc = {};
#pragma unroll
    for (int kk = 0; kk < 2; ++kk) {
      const bf16x8 kb = *(const bf16x8*)&Kt[(td * 16 + l16) * AP + kk * 32 + quad * 8];
      acc = __builtin_amdgcn_mfma_f32_16x16x32_bf16(va[kk], kb, acc, 0, 0, 0);
    }
#pragma unroll
    for (int r = 0; r < 4; ++r)
      dst[(ti * 16 + quad * 4 + r) * 64 + td * 16 + l16] = (short)acc[r];  // [dd][i]
  }
}

// ---------------------------------------------------------------------------
// Pass 3: exclusive prefix scan over chunks (int16 ckv_t, packed pairs).
// Emits prefix as bf16 hi/lo pair buffers, PRE-SWIZZLED (XOR-8 col groups)
// so k_attn async-stages them linearly; plus final_state (scattered 4B ok).
// Numerics identical to the old in-attn split: exact int -> bf16 hi + lo.
// ---------------------------------------------------------------------------
__global__ __launch_bounds__(256) void k_scan(
    const short* __restrict__ ckv, bf16* __restrict__ Ph, bf16* __restrict__ Pl,
    float* __restrict__ fin)
{
  const int idx2 = blockIdx.x * 256 + threadIdx.x;   // bh*2048 + pair
  const int bh = idx2 >> 11, p = idx2 & 2047;
  const int dd = p >> 5, ii0 = (p & 31) << 1;        // element (dd, ii0/ii0+1)
  const int colp = ((((ii0 >> 3) ^ (dd & 7)) << 3) | (ii0 & 7));  // pre-swizzle
  const short* src = ckv + (size_t)bh * 262144 + dd * 64 + ii0;
  bf16* ph = Ph + (size_t)bh * 262144 + dd * 64 + colp;
  bf16* pl = Pl + (size_t)bh * 262144 + dd * 64 + colp;
  int r0 = 0, r1 = 0;
#pragma unroll
  for (int n = 0; n < 64; ++n) {
    const unsigned int w = *(const unsigned int*)(src + (size_t)n * 4096);
    const short a = (short)(w & 0xffff);
    const short bb = (short)(w >> 16);
    const float f0 = (float)r0, f1 = (float)r1;
    const bf16 h0 = (bf16)f0, h1 = (bf16)f1;
    bf16 hv[2] = {h0, h1};
    bf16 lv[2] = {(bf16)(f0 - (float)h0), (bf16)(f1 - (float)h1)};
    *(unsigned int*)(ph + (size_t)n * 4096) = *(unsigned int*)hv;
    *(unsigned int*)(pl + (size_t)n * 4096) = *(unsigned int*)lv;
    r0 += a; r1 += bb;
  }
  float* fb = fin + (size_t)bh * 4096;   // final_state [k][v] = [i][dd]
  fb[ii0 * 64 + dd] = (float)r0;
  fb[(ii0 + 1) * 64 + dd] = (float)r1;
}

// ---------------------------------------------------------------------------
// Pass 4: per-chunk attention via MFMA: O = (Q K^T . mask) V + Q (Phi + Plo).
// P hi/lo now precomputed+pre-swizzled by k_scan: staged via async_ld16
// (linear copy) into unpadded [64][64] LDS, read with Ks-style XOR swizzle.
// ---------------------------------------------------------------------------
__global__ __launch_bounds__(256) void k_attn(
    const bf16* __restrict__ Qws, const bf16* __restrict__ Kws, const bf16* __restrict__ Vws,
    const bf16* __restrict__ Ph, const bf16* __restrict__ Pl, f16* __restrict__ attn)
{
  __shared__ bf16 Ks[64 * 64];   // [t][d], swizzled, async-staged (8KB)
  __shared__ bf16 Vt[64 * AP];   // [dd][t]
  __shared__ bf16 Phs[64 * 64];  // [dd][k], swizzled, async-staged (8KB)
  __shared__ bf16 Pls[64 * 64];  // [dd][k], swizzled, async-staged (8KB)
  __shared__ bf16 Ss[64 * AP];   // scores; reused as f16 O-tile
  const int tid = threadIdx.x;
  const int nchunk = blockIdx.x & 63, bh = blockIdx.x >> 6;
  const int b = bh >> 4, h = bh & 15;
  const size_t tbase = ((size_t)bh * 4096 + (size_t)nchunk * 64) * 64;

  // K rows (source-swizzled) + P hi/lo (pre-swizzled in global -> linear copy)
  {
    const int c8 = tid & 7, r0 = tid >> 3;  // r0: 0..31
    const bf16* gph = Ph + ((size_t)bh * 64 + nchunk) * 4096;
    const bf16* gpl = Pl + ((size_t)bh * 64 + nchunk) * 4096;
#pragma unroll
    for (int it = 0; it < 2; ++it) {
      const int row = it * 32 + r0;
      async_ld16(Kws + tbase + row * 64 + ((c8 ^ (row & 7)) << 3), Ks + row * 64 + (c8 << 3));
      async_ld16(gph + row * 64 + (c8 << 3), Phs + row * 64 + (c8 << 3));
      async_ld16(gpl + row * 64 + (c8 << 3), Pls + row * 64 + (c8 << 3));
    }
  }
  const int wave = tid >> 6, lane = tid & 63;
  const int quad = lane >> 4, l16 = lane & 15;
  const int ti = wave;
  // Q A-fragments direct from global (16B contiguous per lane)
  bf16x8 qa[2];
#pragma unroll
  for (int kk = 0; kk < 2; ++kk)
    qa[kk] = *(const bf16x8*)(Qws + tbase + (ti * 16 + l16) * 64 + kk * 32 + quad * 8);
  // V transpose staging
  {
    const int row = tid >> 2, c0 = (tid & 3) << 4;
    const bf16x8* gv = (const bf16x8*)(Vws + tbase + row * 64 + c0);
    bf16x8 v0 = gv[0], v1 = gv[1];
#pragma unroll
    for (int u = 0; u < 8; ++u) {
      Vt[(c0 + u) * AP + row] = v0[u];
      Vt[(c0 + 8 + u) * AP + row] = v1[u];
    }
  }
  __syncthreads();

  const int sw = l16 & 7;
  // S = Q K^T
  f32x4 sacc[4] = {};
#pragma unroll
  for (int tj = 0; tj < 4; ++tj)
#pragma unroll
    for (int kk = 0; kk < 2; ++kk) {
      const bf16x8 kb = *(const bf16x8*)&Ks[(tj * 16 + l16) * 64 + (((kk * 4 + quad) ^ sw) << 3)];
      sacc[tj] = __builtin_amdgcn_mfma_f32_16x16x32_bf16(qa[kk], kb, sacc[tj], 0, 0, 0);
    }
#pragma unroll
  for (int tj = 0; tj < 4; ++tj)
#pragma unroll
    for (int r = 0; r < 4; ++r) {
      const int i = ti * 16 + quad * 4 + r;
      const int jj = tj * 16 + l16;
      Ss[i * AP + jj] = (bf16)((jj <= i) ? sacc[tj][r] : 0.f);
    }
  __syncthreads();

  // O = S V + Q Phi + Q Plo
  bf16x8 sa[2];
#pragma unroll
  for (int kk = 0; kk < 2; ++kk)
    sa[kk] = *(const bf16x8*)&Ss[(ti * 16 + l16) * AP + kk * 32 + quad * 8];
  f32x4 oacc[4] = {};
#pragma unroll
  for (int td = 0; td < 4; ++td) {
    const int prow = td * 16 + l16;
#pragma unroll
    for (int kk = 0; kk < 2; ++kk) {
      const bf16x8 vb = *(const bf16x8*)&Vt[prow * AP + kk * 32 + quad * 8];
      oacc[td] = __builtin_amdgcn_mfma_f32_16x16x32_bf16(sa[kk], vb, oacc[td], 0, 0, 0);
    }
#pragma unroll
    for (int kk = 0; kk < 2; ++kk) {
      const bf16x8 pb = *(const bf16x8*)&Phs[prow * 64 + (((kk * 4 + quad) ^ sw) << 3)];
      oacc[td] = __builtin_amdgcn_mfma_f32_16x16x32_bf16(qa[kk], pb, oacc[td], 0, 0, 0);
      const bf16x8 pb2 = *(const bf16x8*)&Pls[prow * 64 + (((kk * 4 + quad) ^ sw) << 3)];
      oacc[td] = __builtin_amdgcn_mfma_f32_16x16x32_bf16(qa[kk], pb2, oacc[td], 0, 0, 0);
    }
  }
  __syncthreads();
  f16* Os = (f16*)Ss;
#pragma unroll
  for (int td = 0; td < 4; ++td)
#pragma unroll
    for (int r = 0; r < 4; ++r) {
      const int i = ti * 16 + quad * 4 + r;
      const int dd = td * 16 + l16;
      Os[i * AP + dd] = (f16)oacc[td][r];
    }
  __syncthreads();
  {
    const int i2 = tid >> 2, q4 = tid & 3;
    const int t = nchunk * 64 + i2;
    f16* dst = attn + ((size_t)(b * 4096 + t)) * 1024 + h * 64 + q4 * 16;
    const f16* src = &Os[i2 * AP + q4 * 16];
    *(f16x8*)(dst) = *(const f16x8*)(src);
    *(f16x8*)(dst + 8) = *(const f16x8*)(src + 8);
  }
}

// ---------------------------------------------------------------------------
// Pass 5: output projection GEMM (f16) — 128x128 tile, 1-D grid 512 with
// XCD-aware remap (m = bidl&63 pins each A-panel to one XCD) — R3-proven.
// ---------------------------------------------------------------------------
__global__ __launch_bounds__(256) void k_gemm_out(
    const f16* __restrict__ A, const f16* __restrict__ B, float* __restrict__ out)
{
  __shared__ f16 As[128 * 64];
  __shared__ f16 Bs[128 * 64];
  const int tid = threadIdx.x;
  const int wave = tid >> 6, lane = tid & 63;
  const int quad = lane >> 4, l16 = lane & 15;
  const int bidl = blockIdx.x;
  const int m0 = (bidl & 63) << 7;
  const int n0 = (bidl >> 6) << 7;
  const int wm = (wave >> 1) << 6, wn = (wave & 1) << 6;
  const int r8 = lane >> 3, c8 = lane & 7;
  const int sw = l16 & 7;
  const int srcoff = (c8 ^ r8) * 8;
  f32x4 acc[4][4] = {};

  for (int k0 = 0; k0 < 1024; k0 += 64) {
    __syncthreads();
#pragma unroll
    for (int it = 0; it < 4; ++it) {
      const int row = wave * 32 + it * 8 + r8;
      async_ld16(A + (size_t)(m0 + row) * 1024 + k0 + srcoff, As + row * 64 + c8 * 8);
      async_ld16(B + (size_t)(n0 + row) * 1024 + k0 + srcoff, Bs + row * 64 + c8 * 8);
    }
    __syncthreads();
#pragma unroll
    for (int ks = 0; ks < 64; ks += 32) {
      f16x8 af[4], bg[4];
#pragma unroll
      for (int mi = 0; mi < 4; ++mi)
        af[mi] = *(const f16x8*)&As[(wm + mi * 16 + l16) * 64 + ((((ks >> 3) + quad) ^ sw) << 3)];
#pragma unroll
      for (int ni = 0; ni < 4; ++ni)
        bg[ni] = *(const f16x8*)&Bs[(wn + ni * 16 + l16) * 64 + ((((ks >> 3) + quad) ^ sw) << 3)];
#pragma unroll
      for (int mi = 0; mi < 4; ++mi)
#pragma unroll
        for (int ni = 0; ni < 4; ++ni)
          acc[mi][ni] = __builtin_amdgcn_mfma_f32_16x16x32_f16(af[mi], bg[ni], acc[mi][ni], 0, 0, 0);
    }
  }
#pragma unroll
  for (int mi = 0; mi < 4; ++mi)
#pragma unroll
    for (int ni = 0; ni < 4; ++ni)
#pragma unroll
      for (int r = 0; r < 4; ++r) {
        const int m = m0 + wm + mi * 16 + quad * 4 + r;
        const int n = n0 + wn + ni * 16 + l16;
        out[(size_t)m * 1024 + n] = acc[mi][ni][r];
      }
}

// ---------------------------------------------------------------------------
extern "C" void kernel_launch(void* const* d_in, const int* in_sizes, int n_in,
                              void* d_out, int out_size, void* d_ws, size_t ws_size,
                              hipStream_t stream)
{
  const float* x = (const float*)d_in[0];
  const float* wqkv = (const float*)d_in[1];
  const float* wo = (const float*)d_in[2];
  float* out = (float*)d_out;
  char* ws = (char*)d_ws;

  bf16* xsplit = (bf16*)(ws);
  bf16* wsplit = (bf16*)(ws + 33554432);
  f16*  wo16   = (f16*)(ws + 46137344);
  bf16* Qws    = (bf16*)(ws + 48234496);
  bf16* Kws    = (bf16*)(ws + 65011712);
  bf16* Vws    = (bf16*)(ws + 81788928);
  short* ckv   = (short*)(ws + 98566144);   // 16,777,216 B (int16 chunk-KV, transposed)
  f16*  attn   = (f16*)(ws + 132120576);
  // Ph/Pl reuse the xsplit region (dead after k_gemm_qkv): 2 x 16.78 MB.
  bf16* Ph     = (bf16*)(ws);
  bf16* Pl     = (bf16*)(ws + 16777216);
  float* fin   = out + 8388608;

  k_convert<<<12288, 256, 0, stream>>>(x, wqkv, wo, xsplit, wsplit, wo16);
  k_gemm_qkv<<<1536, 256, 0, stream>>>(xsplit, wsplit, Qws, Kws, Vws);
  k_ckv<<<2048, 256, 0, stream>>>(Kws, Vws, ckv);
  k_scan<<<256, 256, 0, stream>>>(ckv, Ph, Pl, fin);
  k_attn<<<2048, 256, 0, stream>>>(Qws, Kws, Vws, Ph, Pl, attn);
  k_gemm_out<<<512, 256, 0, stream>>>(attn, wo16, out);
}

// Round 7
// 273.957 us; speedup vs baseline: 1.0299x; 1.0299x over previous
//
#include <hip/hip_runtime.h>

typedef __bf16 bf16;
typedef __bf16 bf16x8 __attribute__((ext_vector_type(8)));
typedef _Float16 f16;
typedef _Float16 f16x8 __attribute__((ext_vector_type(8)));
typedef float f32x4 __attribute__((ext_vector_type(4)));
typedef short s16x8 __attribute__((ext_vector_type(8)));

#define SCALE 0.125f
#define AP 72   // bf16 LDS row stride for attn/ckv tiles (64 + 8 pad)
#define CT 128  // bf16 LDS row stride for 128-wide C-tile (aliases As|Bs exactly, 32KB)

// ---------------------------------------------------------------------------
// async global->LDS, 16B per lane (wave-uniform LDS base + lane*16 layout)
// ---------------------------------------------------------------------------
__device__ __forceinline__ void async_ld16(const void* g, void* l) {
  __builtin_amdgcn_global_load_lds((const __attribute__((address_space(1))) void*)g,
                                   (__attribute__((address_space(3))) void*)l, 16, 0, 0);
}

// ---------------------------------------------------------------------------
// Pass 0: convert/split inputs (float4-vectorized).
// ---------------------------------------------------------------------------
__global__ __launch_bounds__(256) void k_convert(
    const float* __restrict__ x, const float* __restrict__ wqkv, const float* __restrict__ wo,
    bf16* __restrict__ xsplit, bf16* __restrict__ wsplit, f16* __restrict__ wo16)
{
  const int N1 = 2097152, N2 = 786432, N3 = 262144;  // in float4 units
  const int i = blockIdx.x * 256 + threadIdx.x;
  if (i < N1) {
    f32x4 v = ((const f32x4*)x)[i];
    int e = i * 4, m = e >> 10, c = e & 1023;
    bf16 hi[4], lo[4];
#pragma unroll
    for (int u = 0; u < 4; ++u) { hi[u] = (bf16)v[u]; lo[u] = (bf16)(v[u] - (float)hi[u]); }
    *(ulong1*)&xsplit[(size_t)m * 2048 + c] = *(ulong1*)hi;
    *(ulong1*)&xsplit[(size_t)m * 2048 + 1024 + c] = *(ulong1*)lo;
  } else if (i < N1 + N2) {
    int j = i - N1;
    f32x4 v = ((const f32x4*)wqkv)[j];
    int e = j * 4, n = e >> 10, c = e & 1023;
    bf16 hi[4], lo[4];
#pragma unroll
    for (int u = 0; u < 4; ++u) { hi[u] = (bf16)v[u]; lo[u] = (bf16)(v[u] - (float)hi[u]); }
    *(ulong1*)&wsplit[(size_t)n * 2048 + c] = *(ulong1*)hi;
    *(ulong1*)&wsplit[(size_t)n * 2048 + 1024 + c] = *(ulong1*)lo;
  } else if (i < N1 + N2 + N3) {
    int j = i - N1 - N2;
    f32x4 v = ((const f32x4*)wo)[j];
    f16 h[4];
#pragma unroll
    for (int u = 0; u < 4; ++u) h[u] = (f16)v[u];
    *(ulong1*)&wo16[(size_t)j * 4] = *(ulong1*)h;
  }
}

// ---------------------------------------------------------------------------
// Pass 1: QKV GEMM (R3-proven: fused 3-term K/V path, conflict-free swizzle,
// full-drain __syncthreads, XCD-aware remap mb = l&63 -> FETCH 79-87MB).
// ---------------------------------------------------------------------------
__global__ __launch_bounds__(256) void k_gemm_qkv(
    const bf16* __restrict__ A, const bf16* __restrict__ B,
    bf16* __restrict__ Qws, bf16* __restrict__ Kws, bf16* __restrict__ Vws)
{
  __shared__ char smem[32768];
  const int tid = threadIdx.x;
  const int wave = tid >> 6, lane = tid & 63;
  const int quad = lane >> 4, l16 = lane & 15;
  // XCD-aware remap: l -> (mb, nbr); mb = l&63 pins each A-panel to one XCD.
  const int l = blockIdx.x;
  int mb, nbr;
  if (l < 1024) { mb = l & 63; nbr = 8 + (l >> 6); }       // K,V blocks first
  else          { const int q = l - 1024; mb = q & 63; nbr = q >> 6; }  // Q
  const int n0 = nbr * 128;
  const int m0 = mb * 128;
  const int wm = (wave >> 1) << 6, wn = (wave & 1) << 6;
  const int region = n0 >> 10;  // 0=q, 1=k, 2=v
  f32x4 acc[4][4] = {};

  if (region == 0) {
    bf16* As = (bf16*)smem;
    bf16* Bs = As + 128 * 64;
    const int r8 = lane >> 3, c8 = lane & 7;
    const int sw = l16 & 7;
    const int srcoff = (c8 ^ r8) * 8;
    for (int k0 = 0; k0 < 1024; k0 += 64) {
      __syncthreads();
#pragma unroll
      for (int it = 0; it < 4; ++it) {
        const int row = wave * 32 + it * 8 + r8;
        async_ld16(A + (size_t)(m0 + row) * 2048 + k0 + srcoff, As + row * 64 + c8 * 8);
        async_ld16(B + (size_t)(n0 + row) * 2048 + k0 + srcoff, Bs + row * 64 + c8 * 8);
      }
      __syncthreads();
#pragma unroll
      for (int ks = 0; ks < 64; ks += 32) {
        bf16x8 af[4], bg[4];
#pragma unroll
        for (int mi = 0; mi < 4; ++mi)
          af[mi] = *(const bf16x8*)&As[(wm + mi * 16 + l16) * 64 + ((((ks >> 3) + quad) ^ sw) << 3)];
#pragma unroll
        for (int ni = 0; ni < 4; ++ni)
          bg[ni] = *(const bf16x8*)&Bs[(wn + ni * 16 + l16) * 64 + ((((ks >> 3) + quad) ^ sw) << 3)];
#pragma unroll
        for (int mi = 0; mi < 4; ++mi)
#pragma unroll
          for (int ni = 0; ni < 4; ++ni)
            acc[mi][ni] = __builtin_amdgcn_mfma_f32_16x16x32_bf16(af[mi], bg[ni], acc[mi][ni], 0, 0, 0);
      }
    }
  } else {
    bf16* Ah = (bf16*)smem;
    bf16* Al = Ah + 128 * 32;
    bf16* Bh = Al + 128 * 32;
    bf16* Bl = Bh + 128 * 32;
    const int rr0 = tid >> 2;
    const int sl = tid & 3;
    const int rsw = quad ^ ((l16 >> 1) & 3);
    for (int k0 = 0; k0 < 1024; k0 += 32) {
      __syncthreads();
#pragma unroll
      for (int rr = 0; rr < 2; ++rr) {
        const int row = rr * 64 + rr0;
        const int soff = ((sl ^ ((row >> 1) & 3)) << 3);
        const bf16* arow = A + (size_t)(m0 + row) * 2048 + k0 + soff;
        const bf16* brow = B + (size_t)(n0 + row) * 2048 + k0 + soff;
        async_ld16(arow,        Ah + row * 32 + sl * 8);
        async_ld16(arow + 1024, Al + row * 32 + sl * 8);
        async_ld16(brow,        Bh + row * 32 + sl * 8);
        async_ld16(brow + 1024, Bl + row * 32 + sl * 8);
      }
      __syncthreads();
#pragma unroll
      for (int cb = 0; cb < 3; ++cb) {
        const bf16* Asrc = (cb == 1) ? Al : Ah;
        const bf16* Bsrc = (cb == 2) ? Bl : Bh;
        bf16x8 af[4], bg[4];
#pragma unroll
        for (int mi = 0; mi < 4; ++mi)
          af[mi] = *(const bf16x8*)&Asrc[(wm + mi * 16 + l16) * 32 + (rsw << 3)];
#pragma unroll
        for (int ni = 0; ni < 4; ++ni)
          bg[ni] = *(const bf16x8*)&Bsrc[(wn + ni * 16 + l16) * 32 + (rsw << 3)];
#pragma unroll
        for (int mi = 0; mi < 4; ++mi)
#pragma unroll
          for (int ni = 0; ni < 4; ++ni)
            acc[mi][ni] = __builtin_amdgcn_mfma_f32_16x16x32_bf16(af[mi], bg[ni], acc[mi][ni], 0, 0, 0);
      }
    }
  }

  bf16* Ct = (bf16*)smem;
  __syncthreads();
#pragma unroll
  for (int mi = 0; mi < 4; ++mi) {
    const int ml = wm + mi * 16 + quad * 4;
#pragma unroll
    for (int ni = 0; ni < 4; ++ni) {
      const int nl = wn + ni * 16 + l16;
#pragma unroll
      for (int r = 0; r < 4; ++r) {
        const float v = acc[mi][ni][r];
        bf16 o;
        if (region == 0) o = (bf16)(v * SCALE);
        else             o = (bf16)((v >= 0.f) ? 1.f : -1.f);
        Ct[(ml + r) * CT + nl] = o;
      }
    }
  }
  __syncthreads();
  {
    const int row = tid >> 1, half = tid & 1;
    const int nn = (n0 & 1023) + half * 64;
    const int h = nn >> 6;
    const int b = m0 >> 12, t = (m0 & 4095) + row;
    bf16* base = (region == 0) ? Qws : (region == 1) ? Kws : Vws;
    bf16* dst = base + ((size_t)(b * 16 + h) * 4096 + t) * 64;
    const bf16* src = &Ct[row * CT + half * 64];
#pragma unroll
    for (int u = 0; u < 8; ++u)
      *(bf16x8*)(dst + u * 8) = *(const bf16x8*)(src + u * 8);
  }
}

// ---------------------------------------------------------------------------
// Pass 2: per-chunk KV outer product via MFMA -> int16, TRANSPOSED output
// (R6-proven): ckv_t[dd(v)][i(k)] = sum_t V[t][dd] K[t][i]. Exact ints.
// ---------------------------------------------------------------------------
__global__ __launch_bounds__(256) void k_ckv(
    const bf16* __restrict__ Kws, const bf16* __restrict__ Vws, short* __restrict__ ckv)
{
  __shared__ bf16 Kt[64 * AP];  // [i][t]
  __shared__ bf16 Vt[64 * AP];  // [dd][t]
  const int tid = threadIdx.x;
  const int nchunk = blockIdx.x & 63, bh = blockIdx.x >> 6;
  const size_t tbase = ((size_t)bh * 4096 + (size_t)nchunk * 64) * 64;
  const int row = tid >> 2, c0 = (tid & 3) << 4;
  {
    const bf16x8* gk = (const bf16x8*)(Kws + tbase + row * 64 + c0);
    const bf16x8* gv = (const bf16x8*)(Vws + tbase + row * 64 + c0);
    bf16x8 k0 = gk[0], k1 = gk[1], v0 = gv[0], v1 = gv[1];
#pragma unroll
    for (int u = 0; u < 8; ++u) {
      Kt[(c0 + u) * AP + row] = k0[u];
      Kt[(c0 + 8 + u) * AP + row] = k1[u];
      Vt[(c0 + u) * AP + row] = v0[u];
      Vt[(c0 + 8 + u) * AP + row] = v1[u];
    }
  }
  __syncthreads();
  const int wave = tid >> 6, lane = tid & 63;
  const int quad = lane >> 4, l16 = lane & 15;
  const int ti = wave;
  bf16x8 va[2];   // A-operand: V rows (dd)
#pragma unroll
  for (int kk = 0; kk < 2; ++kk)
    va[kk] = *(const bf16x8*)&Vt[(ti * 16 + l16) * AP + kk * 32 + quad * 8];
  short* dst = ckv + ((size_t)bh * 64 + nchunk) * 4096;
#pragma unroll
  for (int td = 0; td < 4; ++td) {
    f32x4 acc = {};
#pragma unroll
    for (int kk = 0; kk < 2; ++kk) {
      const bf16x8 kb = *(const bf16x8*)&Kt[(td * 16 + l16) * AP + kk * 32 + quad * 8];
      acc = __builtin_amdgcn_mfma_f32_16x16x32_bf16(va[kk], kb, acc, 0, 0, 0);
    }
#pragma unroll
    for (int r = 0; r < 4; ++r)
      dst[(ti * 16 + quad * 4 + r) * 64 + td * 16 + l16] = (short)acc[r];  // [dd][i]
  }
}

// ---------------------------------------------------------------------------
// Pass 3: in-place exclusive prefix scan over chunks (int16 ckv_t, packed
// pairs along i) + final_state. R3 traffic (32MB RMW), R6-proven fin layout.
// ---------------------------------------------------------------------------
__global__ __launch_bounds__(256) void k_scan(short* __restrict__ ckv, float* __restrict__ fin)
{
  const int idx2 = blockIdx.x * 256 + threadIdx.x;   // bh*2048 + pair
  const int bh = idx2 >> 11, p = idx2 & 2047;
  const int dd = p >> 5, ii0 = (p & 31) << 1;        // element (dd, ii0/ii0+1)
  short* q = ckv + (size_t)bh * 262144 + dd * 64 + ii0;
  int r0 = 0, r1 = 0;
#pragma unroll
  for (int n = 0; n < 64; ++n) {
    unsigned int w = *(unsigned int*)(q + (size_t)n * 4096);
    const short a = (short)(w & 0xffff);
    const short bb = (short)(w >> 16);
    *(unsigned int*)(q + (size_t)n * 4096) =
        ((unsigned int)(unsigned short)(short)r0) | (((unsigned int)(unsigned short)(short)r1) << 16);
    r0 += a; r1 += bb;
  }
  float* fb = fin + (size_t)bh * 4096;   // final_state [k][v] = [i][dd]
  fb[ii0 * 64 + dd] = (float)r0;
  fb[(ii0 + 1) * 64 + dd] = (float)r1;
}

// ---------------------------------------------------------------------------
// Pass 4: per-chunk attention via MFMA: O = (Q K^T . mask) V + Q (Phi + Plo).
// pref is transposed [dd][i] -> P staging: coalesced s16x8 loads + vectorized
// bf16x8 LDS stores (replaces 32 scalar AP-stride stores). Read side = R3.
// ---------------------------------------------------------------------------
__global__ __launch_bounds__(256) void k_attn(
    const bf16* __restrict__ Qws, const bf16* __restrict__ Kws, const bf16* __restrict__ Vws,
    const short* __restrict__ pref, f16* __restrict__ attn)
{
  __shared__ bf16 Ks[64 * 64];  // [t][d], swizzled, async-staged (8KB)
  __shared__ bf16 Vt[64 * AP];  // [dd][t]
  __shared__ bf16 Ph[64 * AP];  // [dd][i] hi
  __shared__ bf16 Pl[64 * AP];  // [dd][i] lo
  __shared__ bf16 Ss[64 * AP];  // scores; reused as f16 O-tile
  const int tid = threadIdx.x;
  const int nchunk = blockIdx.x & 63, bh = blockIdx.x >> 6;
  const int b = bh >> 4, h = bh & 15;
  const size_t tbase = ((size_t)bh * 4096 + (size_t)nchunk * 64) * 64;

  // K rows via async (64 rows x 128B = 512 16B-chunks; 2 per thread)
  {
    const int c8 = tid & 7, r0 = tid >> 3;  // r0: 0..31
#pragma unroll
    for (int it = 0; it < 2; ++it) {
      const int row = it * 32 + r0;
      async_ld16(Kws + tbase + row * 64 + ((c8 ^ (row & 7)) << 3), Ks + row * 64 + (c8 << 3));
    }
  }
  const int wave = tid >> 6, lane = tid & 63;
  const int quad = lane >> 4, l16 = lane & 15;
  const int ti = wave;
  // Q A-fragments direct from global (16B contiguous per lane)
  bf16x8 qa[2];
#pragma unroll
  for (int kk = 0; kk < 2; ++kk)
    qa[kk] = *(const bf16x8*)(Qws + tbase + (ti * 16 + l16) * 64 + kk * 32 + quad * 8);
  // V transpose staging (unchanged from R3)
  {
    const int row = tid >> 2, c0 = (tid & 3) << 4;
    const bf16x8* gv = (const bf16x8*)(Vws + tbase + row * 64 + c0);
    bf16x8 v0 = gv[0], v1 = gv[1];
#pragma unroll
    for (int u = 0; u < 8; ++u) {
      Vt[(c0 + u) * AP + row] = v0[u];
      Vt[(c0 + 8 + u) * AP + row] = v1[u];
    }
  }
  // P hi/lo staging from transposed pref: coalesced loads, vector stores
  {
    const int dd = tid >> 2, i0 = (tid & 3) << 4;
    const short* gp = pref + ((size_t)bh * 64 + nchunk) * 4096 + dd * 64 + i0;
    s16x8 p0 = *(const s16x8*)(gp);
    s16x8 p1 = *(const s16x8*)(gp + 8);
    bf16 h8[8], l8[8];
#pragma unroll
    for (int u = 0; u < 8; ++u) {
      const float p = (float)p0[u];
      h8[u] = (bf16)p;
      l8[u] = (bf16)(p - (float)h8[u]);
    }
    *(bf16x8*)&Ph[dd * AP + i0] = *(bf16x8*)h8;
    *(bf16x8*)&Pl[dd * AP + i0] = *(bf16x8*)l8;
#pragma unroll
    for (int u = 0; u < 8; ++u) {
      const float p = (float)p1[u];
      h8[u] = (bf16)p;
      l8[u] = (bf16)(p - (float)h8[u]);
    }
    *(bf16x8*)&Ph[dd * AP + i0 + 8] = *(bf16x8*)h8;
    *(bf16x8*)&Pl[dd * AP + i0 + 8] = *(bf16x8*)l8;
  }
  __syncthreads();

  const int sw = l16 & 7;
  // S = Q K^T
  f32x4 sacc[4] = {};
#pragma unroll
  for (int tj = 0; tj < 4; ++tj)
#pragma unroll
    for (int kk = 0; kk < 2; ++kk) {
      const bf16x8 kb = *(const bf16x8*)&Ks[(tj * 16 + l16) * 64 + (((kk * 4 + quad) ^ sw) << 3)];
      sacc[tj] = __builtin_amdgcn_mfma_f32_16x16x32_bf16(qa[kk], kb, sacc[tj], 0, 0, 0);
    }
#pragma unroll
  for (int tj = 0; tj < 4; ++tj)
#pragma unroll
    for (int r = 0; r < 4; ++r) {
      const int i = ti * 16 + quad * 4 + r;
      const int jj = tj * 16 + l16;
      Ss[i * AP + jj] = (bf16)((jj <= i) ? sacc[tj][r] : 0.f);
    }
  __syncthreads();

  // O = S V + Q Phi + Q Plo
  bf16x8 sa[2];
#pragma unroll
  for (int kk = 0; kk < 2; ++kk)
    sa[kk] = *(const bf16x8*)&Ss[(ti * 16 + l16) * AP + kk * 32 + quad * 8];
  f32x4 oacc[4] = {};
#pragma unroll
  for (int td = 0; td < 4; ++td) {
    const int prow = td * 16 + l16;
#pragma unroll
    for (int kk = 0; kk < 2; ++kk) {
      const bf16x8 vb = *(const bf16x8*)&Vt[prow * AP + kk * 32 + quad * 8];
      oacc[td] = __builtin_amdgcn_mfma_f32_16x16x32_bf16(sa[kk], vb, oacc[td], 0, 0, 0);
    }
#pragma unroll
    for (int kk = 0; kk < 2; ++kk) {
      const bf16x8 pb = *(const bf16x8*)&Ph[prow * AP + kk * 32 + quad * 8];
      oacc[td] = __builtin_amdgcn_mfma_f32_16x16x32_bf16(qa[kk], pb, oacc[td], 0, 0, 0);
      const bf16x8 pb2 = *(const bf16x8*)&Pl[prow * AP + kk * 32 + quad * 8];
      oacc[td] = __builtin_amdgcn_mfma_f32_16x16x32_bf16(qa[kk], pb2, oacc[td], 0, 0, 0);
    }
  }
  __syncthreads();
  f16* Os = (f16*)Ss;
#pragma unroll
  for (int td = 0; td < 4; ++td)
#pragma unroll
    for (int r = 0; r < 4; ++r) {
      const int i = ti * 16 + quad * 4 + r;
      const int dd = td * 16 + l16;
      Os[i * AP + dd] = (f16)oacc[td][r];
    }
  __syncthreads();
  {
    const int i2 = tid >> 2, q4 = tid & 3;
    const int t = nchunk * 64 + i2;
    f16* dst = attn + ((size_t)(b * 4096 + t)) * 1024 + h * 64 + q4 * 16;
    const f16* src = &Os[i2 * AP + q4 * 16];
    *(f16x8*)(dst) = *(const f16x8*)(src);
    *(f16x8*)(dst + 8) = *(const f16x8*)(src + 8);
  }
}

// ---------------------------------------------------------------------------
// Pass 5: output projection GEMM (f16) — 128x128 tile, 1-D grid 512 with
// XCD-aware remap (m = bidl&63 pins each A-panel to one XCD) — R3-proven.
// ---------------------------------------------------------------------------
__global__ __launch_bounds__(256) void k_gemm_out(
    const f16* __restrict__ A, const f16* __restrict__ B, float* __restrict__ out)
{
  __shared__ f16 As[128 * 64];
  __shared__ f16 Bs[128 * 64];
  const int tid = threadIdx.x;
  const int wave = tid >> 6, lane = tid & 63;
  const int quad = lane >> 4, l16 = lane & 15;
  const int bidl = blockIdx.x;
  const int m0 = (bidl & 63) << 7;
  const int n0 = (bidl >> 6) << 7;
  const int wm = (wave >> 1) << 6, wn = (wave & 1) << 6;
  const int r8 = lane >> 3, c8 = lane & 7;
  const int sw = l16 & 7;
  const int srcoff = (c8 ^ r8) * 8;
  f32x4 acc[4][4] = {};

  for (int k0 = 0; k0 < 1024; k0 += 64) {
    __syncthreads();
#pragma unroll
    for (int it = 0; it < 4; ++it) {
      const int row = wave * 32 + it * 8 + r8;
      async_ld16(A + (size_t)(m0 + row) * 1024 + k0 + srcoff, As + row * 64 + c8 * 8);
      async_ld16(B + (size_t)(n0 + row) * 1024 + k0 + srcoff, Bs + row * 64 + c8 * 8);
    }
    __syncthreads();
#pragma unroll
    for (int ks = 0; ks < 64; ks += 32) {
      f16x8 af[4], bg[4];
#pragma unroll
      for (int mi = 0; mi < 4; ++mi)
        af[mi] = *(const f16x8*)&As[(wm + mi * 16 + l16) * 64 + ((((ks >> 3) + quad) ^ sw) << 3)];
#pragma unroll
      for (int ni = 0; ni < 4; ++ni)
        bg[ni] = *(const f16x8*)&Bs[(wn + ni * 16 + l16) * 64 + ((((ks >> 3) + quad) ^ sw) << 3)];
#pragma unroll
      for (int mi = 0; mi < 4; ++mi)
#pragma unroll
        for (int ni = 0; ni < 4; ++ni)
          acc[mi][ni] = __builtin_amdgcn_mfma_f32_16x16x32_f16(af[mi], bg[ni], acc[mi][ni], 0, 0, 0);
    }
  }
#pragma unroll
  for (int mi = 0; mi < 4; ++mi)
#pragma unroll
    for (int ni = 0; ni < 4; ++ni)
#pragma unroll
      for (int r = 0; r < 4; ++r) {
        const int m = m0 + wm + mi * 16 + quad * 4 + r;
        const int n = n0 + wn + ni * 16 + l16;
        out[(size_t)m * 1024 + n] = acc[mi][ni][r];
      }
}

// ---------------------------------------------------------------------------
extern "C" void kernel_launch(void* const* d_in, const int* in_sizes, int n_in,
                              void* d_out, int out_size, void* d_ws, size_t ws_size,
                              hipStream_t stream)
{
  const float* x = (const float*)d_in[0];
  const float* wqkv = (const float*)d_in[1];
  const float* wo = (const float*)d_in[2];
  float* out = (float*)d_out;
  char* ws = (char*)d_ws;

  bf16* xsplit = (bf16*)(ws);
  bf16* wsplit = (bf16*)(ws + 33554432);
  f16*  wo16   = (f16*)(ws + 46137344);
  bf16* Qws    = (bf16*)(ws + 48234496);
  bf16* Kws    = (bf16*)(ws + 65011712);
  bf16* Vws    = (bf16*)(ws + 81788928);
  short* ckv   = (short*)(ws + 98566144);   // 16,777,216 B (int16 chunk-KV, transposed)
  f16*  attn   = (f16*)(ws + 132120576);
  float* fin   = out + 8388608;

  k_convert<<<12288, 256, 0, stream>>>(x, wqkv, wo, xsplit, wsplit, wo16);
  k_gemm_qkv<<<1536, 256, 0, stream>>>(xsplit, wsplit, Qws, Kws, Vws);
  k_ckv<<<2048, 256, 0, stream>>>(Kws, Vws, ckv);
  k_scan<<<256, 256, 0, stream>>>(ckv, fin);
  k_attn<<<2048, 256, 0, stream>>>(Qws, Kws, Vws, ckv, attn);
  k_gemm_out<<<512, 256, 0, stream>>>(attn, wo16, out);
}